// Round 1
// 1371.840 us; speedup vs baseline: 1.2037x; 1.2037x over previous
//
#include <hip/hip_runtime.h>

typedef __bf16 bf16;
typedef __bf16 bf16x8 __attribute__((ext_vector_type(8)));
typedef __bf16 bf16x4 __attribute__((ext_vector_type(4)));
typedef float floatx4 __attribute__((ext_vector_type(4)));

#define MFMA16(a, b, c) __builtin_amdgcn_mfma_f32_16x16x32_bf16(a, b, c, 0, 0, 0)

// async global->LDS, 16 bytes/lane, dest = wave-uniform base + lane*16
#define GLOAD_LDS16(g, l)                                          \
  __builtin_amdgcn_global_load_lds(                                \
      (const __attribute__((address_space(1))) void*)(g),          \
      (__attribute__((address_space(3))) void*)(l), 16, 0, 0)

#define BAR() __builtin_amdgcn_s_barrier()
#define SCHED0() __builtin_amdgcn_sched_barrier(0)
#define LGKM0()                                        \
  do {                                                 \
    asm volatile("s_waitcnt lgkmcnt(0)" ::: "memory"); \
    __builtin_amdgcn_sched_barrier(0);                 \
  } while (0)
#define VM6() asm volatile("s_waitcnt vmcnt(6)" ::: "memory")

#define MFMA_PHASE(HM, HN, BB)                                            \
  do {                                                                    \
    __builtin_amdgcn_s_setprio(1);                                        \
    _Pragma("unroll") for (int kk = 0; kk < 2; ++kk)                      \
        _Pragma("unroll") for (int mf = 0; mf < 4; ++mf)                  \
            _Pragma("unroll") for (int nf = 0; nf < 2; ++nf)              \
                acc[HM][HN][mf][nf] =                                     \
        MFMA16(af[kk][mf], BB[kk][nf], acc[HM][HN][mf][nf]);              \
    __builtin_amdgcn_s_setprio(0);                                        \
  } while (0)

// ---------------------------------------------------------------------------
// fp32 -> bf16 elementwise convert (8 elems/thread)
// ---------------------------------------------------------------------------
__global__ __launch_bounds__(256) void cvt_bf16(const float* __restrict__ src,
                                                bf16* __restrict__ dst, long n) {
  const long i = ((long)blockIdx.x * 256 + threadIdx.x) * 8;
  if (i >= n) return;
  float4 a = *(const float4*)&src[i];
  float4 b = *(const float4*)&src[i + 4];
  bf16x8 o = {(bf16)a.x, (bf16)a.y, (bf16)a.z, (bf16)a.w,
              (bf16)b.x, (bf16)b.y, (bf16)b.z, (bf16)b.w};
  *(bf16x8*)&dst[i] = o;
}

// ---------------------------------------------------------------------------
// 256x256-tile 8-phase NT GEMM (m201 structure): C[m][n] = epi(sum_k A[m][k]*B[n][k])
// 512 threads = 8 waves (2M x 4N). BK=64, double-buffered 128 KiB LDS.
// st_16x32 swizzle: lds byte ^= ((byte>>9)&1)<<5, realized as linear
// global_load_lds dest + inverse-swizzled global source + swizzled ds_read.
// Counted vmcnt(6) at phases 3/7 only (3 half-tiles in flight).
// Per-wave C: rows {wm*64..+63} u {128+wm*64..+63}, cols {wn*32..+31} u {128+wn*32..+31}
// so each LDS half-tile retires after exactly one phase:
//   A-h0 read ph0 -> staged ph1 ; B-h0 read ph0 -> staged ph2 ;
//   B-h1 read ph1 -> staged ph3 ; A-h1 read ph2 -> staged ph4 (next buf: +4).
// EPI: 0 = silu -> bf16, 1 = sigmoid -> bf16, 2 = identity -> fp32
// ---------------------------------------------------------------------------
template <int EPI>
__global__ __launch_bounds__(512, 2) void gemm256(const bf16* __restrict__ A,
                                                  const bf16* __restrict__ B,
                                                  void* __restrict__ Cv,
                                                  int N, int K) {
  __shared__ bf16 AS[2][256 * 64];
  __shared__ bf16 BS[2][256 * 64];
  const int tid = threadIdx.x;
  const int wave = tid >> 6, lane = tid & 63;
  const int quad = lane >> 4, l16 = lane & 15;
  const int wm = wave >> 2, wn = wave & 3;
  const int cswz = (l16 & 4) << 2;                       // read-side col XOR (elems)
  const int gc = ((lane & 7) * 8) ^ ((lane & 32) >> 1);  // stage-side source col (elems)

  // bijective XCD-aware block swizzle (m204 variant)
  int wg = blockIdx.x;
  {
    const int nwg = gridDim.x;
    const int q = nwg >> 3, r = nwg & 7, xcd = wg & 7, idx = wg >> 3;
    wg = (xcd < r ? xcd * (q + 1) : r * (q + 1) + (xcd - r) * q) + idx;
  }
  const int nbn = N >> 8;
  const int bm = wg / nbn, bn = wg - bm * nbn;

  const bf16* gA = A + (long)(bm * 256) * K;
  const bf16* gB = B + (long)(bn * 256) * K;

  auto stA = [&](int buf, int h, int kt) {
#pragma unroll
    for (int j = 0; j < 2; ++j) {
      const int rb = h * 128 + j * 64 + wave * 8;  // wave-uniform LDS row base
      GLOAD_LDS16(gA + (long)(rb + (lane >> 3)) * K + kt * 64 + gc,
                  &AS[buf][rb * 64]);
    }
  };
  auto stB = [&](int buf, int h, int kt) {
#pragma unroll
    for (int j = 0; j < 2; ++j) {
      const int rb = h * 128 + j * 64 + wave * 8;
      GLOAD_LDS16(gB + (long)(rb + (lane >> 3)) * K + kt * 64 + gc,
                  &BS[buf][rb * 64]);
    }
  };

  bf16x8 af[2][4], b0[2][2], b1[2][2];
  floatx4 acc[2][2][4][2] = {};

  auto rdA = [&](int buf, int hm) {
#pragma unroll
    for (int kk = 0; kk < 2; ++kk)
#pragma unroll
      for (int mf = 0; mf < 4; ++mf) {
        const int R = hm * 128 + wm * 64 + mf * 16 + l16;
        af[kk][mf] =
            *(const bf16x8*)&AS[buf][R * 64 + ((kk * 32 + quad * 8) ^ cswz)];
      }
  };
  auto rdB = [&](int buf, int hn, bf16x8 (&bb)[2][2]) {
#pragma unroll
    for (int kk = 0; kk < 2; ++kk)
#pragma unroll
      for (int nf = 0; nf < 2; ++nf) {
        const int R = hn * 128 + wn * 32 + nf * 16 + l16;
        bb[kk][nf] =
            *(const bf16x8*)&BS[buf][R * 64 + ((kk * 32 + quad * 8) ^ cswz)];
      }
  };

  const int NT = K >> 6;   // number of K=64 tiles
  const int NI = NT >> 1;  // 2 tiles per iteration

  // prologue: tile0 {A0,A1,B0,B1} -> buf0 ; tile1 {A0,B0,B1} -> buf1 (A1 at ph0)
  stA(0, 0, 0); stA(0, 1, 0); stB(0, 0, 0); stB(0, 1, 0);
  stA(1, 0, 1); stB(1, 0, 1); stB(1, 1, 1);
  VM6();  // oldest 8 loads = tile0 complete; 6 in flight
  BAR();

  for (int it = 0; it < NI; ++it) {
    const int t1 = 2 * it + 1;
    const int t2 = (2 * it + 2 < NT) ? 2 * it + 2 : NT - 1;  // clamped tail restage
    const int t3 = (2 * it + 3 < NT) ? 2 * it + 3 : NT - 1;
    // ph0: quadrant (0,0) of tile 2it (buf0); finish tile 2it+1 staging
    rdA(0, 0); rdB(0, 0, b0);
    stA(1, 1, t1);
    SCHED0(); BAR(); LGKM0();
    MFMA_PHASE(0, 0, b0);
    BAR();
    // ph1: (0,1); stage next-buf0 A-h0
    rdB(0, 1, b1);
    stA(0, 0, t2);
    SCHED0(); BAR(); LGKM0();
    MFMA_PHASE(0, 1, b1);
    BAR();
    // ph2: (1,0); stage next-buf0 B-h0
    rdA(0, 1);
    stB(0, 0, t2);
    SCHED0(); BAR(); LGKM0();
    MFMA_PHASE(1, 0, b0);
    BAR();
    // ph3: (1,1); stage next-buf0 B-h1; counted wait -> buf1 (tile 2it+1) complete
    stB(0, 1, t2);
    VM6(); SCHED0(); BAR(); SCHED0();
    MFMA_PHASE(1, 1, b1);
    BAR();
    // ph4: quadrant (0,0) of tile 2it+1 (buf1); stage next-buf0 A-h1
    rdA(1, 0); rdB(1, 0, b0);
    stA(0, 1, t2);
    SCHED0(); BAR(); LGKM0();
    MFMA_PHASE(0, 0, b0);
    BAR();
    // ph5: (0,1); stage next-buf1 A-h0
    rdB(1, 1, b1);
    stA(1, 0, t3);
    SCHED0(); BAR(); LGKM0();
    MFMA_PHASE(0, 1, b1);
    BAR();
    // ph6: (1,0); stage next-buf1 B-h0
    rdA(1, 1);
    stB(1, 0, t3);
    SCHED0(); BAR(); LGKM0();
    MFMA_PHASE(1, 0, b0);
    BAR();
    // ph7: (1,1); stage next-buf1 B-h1; counted wait -> next buf0 complete
    stB(1, 1, t3);
    VM6(); SCHED0(); BAR(); SCHED0();
    MFMA_PHASE(1, 1, b1);
    BAR();
  }

#pragma unroll
  for (int hm = 0; hm < 2; ++hm)
#pragma unroll
    for (int hn = 0; hn < 2; ++hn)
#pragma unroll
      for (int mf = 0; mf < 4; ++mf)
#pragma unroll
        for (int nf = 0; nf < 2; ++nf)
#pragma unroll
          for (int r = 0; r < 4; ++r) {
            const int row = bm * 256 + hm * 128 + wm * 64 + mf * 16 + quad * 4 + r;
            const int col = bn * 256 + hn * 128 + wn * 32 + nf * 16 + l16;
            const float v = acc[hm][hn][mf][nf][r];
            if constexpr (EPI == 0) {
              ((bf16*)Cv)[(long)row * N + col] = (bf16)(v / (1.f + __expf(-v)));
            } else if constexpr (EPI == 1) {
              ((bf16*)Cv)[(long)row * N + col] = (bf16)(1.f / (1.f + __expf(-v)));
            } else {
              ((float*)Cv)[(long)row * N + col] = v;
            }
          }
}

// ---------------------------------------------------------------------------
// Build kT[h][d][t] and vT[h][e][t] (bf16) from qkvb[t][h*384 + {128+d, 256+e}]
// ---------------------------------------------------------------------------
__global__ __launch_bounds__(256) void transpose_kv(const bf16* __restrict__ qkvb,
                                                    bf16* __restrict__ kT,
                                                    bf16* __restrict__ vT) {
  __shared__ bf16 tile[64][72];
  const int tid = threadIdx.x;
  const int t0 = blockIdx.x * 64;
  const int qz = blockIdx.y;
  const int h = blockIdx.z;
  const int srccol = h * 384 + 128 + (qz >> 1) * 128 + (qz & 1) * 64;
  const int row = tid >> 2, cb = (tid & 3) * 16;
#pragma unroll
  for (int i = 0; i < 2; ++i)
    *(bf16x8*)&tile[row][cb + i * 8] =
        *(const bf16x8*)&qkvb[(long)(t0 + row) * 12288 + srccol + cb + i * 8];
  __syncthreads();
  bf16* dst = (qz >= 2) ? vT : kT;
  const int ch = (qz & 1) * 64 + (tid >> 2);
#pragma unroll
  for (int i = 0; i < 2; ++i) {
    bf16x8 v;
#pragma unroll
    for (int j = 0; j < 8; ++j) v[j] = tile[cb + i * 8 + j][tid >> 2];
    *(bf16x8*)&dst[((long)h * 128 + ch) * 4096 + t0 + cb + i * 8] = v;
  }
}

// ---------------------------------------------------------------------------
// MT[h][b][e][d] = sum_i v[i][e] * (exp(-s*(255-i)) * k[i][d]),  fp32
// ---------------------------------------------------------------------------
__global__ __launch_bounds__(256) void kv_blocks(const bf16* __restrict__ kT,
                                                 const bf16* __restrict__ vT,
                                                 const float* __restrict__ slope,
                                                 float* __restrict__ MT) {
  __shared__ float kdec[256];
  const int tid = threadIdx.x;
  const int b = blockIdx.x, h = blockIdx.y;
  const float s = slope[h];
  if (tid < 256) kdec[tid] = __expf(-s * (float)(255 - tid));
  __syncthreads();
  const int wave = tid >> 6, lane = tid & 63;
  const int quad = lane >> 4, l16 = lane & 15;
  const int we = (wave & 1) * 64, wd = (wave >> 1) * 64;
  floatx4 acc[4][4] = {};
  for (int kc = 0; kc < 8; ++kc) {
    const int ioff = kc * 32 + quad * 8;
    bf16x8 af[4], bfr[4];
#pragma unroll
    for (int mt = 0; mt < 4; ++mt)
      af[mt] = *(const bf16x8*)&vT[((long)h * 128 + we + mt * 16 + l16) * 4096 +
                                   b * 256 + ioff];
#pragma unroll
    for (int nt = 0; nt < 4; ++nt) {
      bf16x8 k8 = *(const bf16x8*)&kT[((long)h * 128 + wd + nt * 16 + l16) * 4096 +
                                      b * 256 + ioff];
      bf16x8 kb;
#pragma unroll
      for (int j = 0; j < 8; ++j) kb[j] = (bf16)((float)k8[j] * kdec[ioff + j]);
      bfr[nt] = kb;
    }
#pragma unroll
    for (int mt = 0; mt < 4; ++mt)
#pragma unroll
      for (int nt = 0; nt < 4; ++nt)
        acc[mt][nt] = MFMA16(af[mt], bfr[nt], acc[mt][nt]);
  }
#pragma unroll
  for (int mt = 0; mt < 4; ++mt)
#pragma unroll
    for (int nt = 0; nt < 4; ++nt)
#pragma unroll
      for (int r = 0; r < 4; ++r) {
        const int e = we + mt * 16 + quad * 4 + r;
        const int d = wd + nt * 16 + l16;
        MT[(((long)h * 16 + b) * 128 + e) * 128 + d] = acc[mt][nt][r];
      }
}

// ---------------------------------------------------------------------------
// ST[h][b][e][d] = KV_b[d][e] (bf16); KV_0 = kv_cache, KV_{b+1}=bd*KV_b + M_b
// ---------------------------------------------------------------------------
__global__ __launch_bounds__(256) void kv_scan(const float* __restrict__ MT,
                                               const float* __restrict__ kvc,
                                               const float* __restrict__ slope,
                                               bf16* __restrict__ ST) {
  const long idx = (long)blockIdx.x * 256 + threadIdx.x;
  const int d = idx & 127;
  const int e = (int)((idx >> 7) & 127);
  const int h = (int)(idx >> 14);
  const float s = slope[h];
  const float bd = __expf(-s * 256.f);
  float kv = kvc[((long)h * 128 + d) * 128 + e];
#pragma unroll
  for (int b = 0; b < 16; ++b) {
    const long o = (((long)h * 16 + b) * 128 + e) * 128 + d;
    ST[o] = (bf16)kv;
    kv = bd * kv + MT[o];
  }
}

// ---------------------------------------------------------------------------
// Per-(head,block) attention output -> hidden fp32 [t][h*128+e]
// ---------------------------------------------------------------------------
__global__ __launch_bounds__(512) void attn_out(const bf16* __restrict__ qkvb,
                                                const bf16* __restrict__ vT,
                                                const bf16* __restrict__ ST,
                                                const float* __restrict__ slope,
                                                float* __restrict__ hidden) {
  __shared__ float ddt[257];
  __shared__ bf16 sbuf[8][32][72];
  const int tid = threadIdx.x;
  const int b = blockIdx.x, h = blockIdx.y;
  const float s = slope[h];
  if (tid < 257) ddt[tid] = __expf(-s * (float)tid);
  __syncthreads();
  const int wave = tid >> 6, lane = tid & 63;
  const int quad = lane >> 4, l16 = lane & 15;
  const int iw = wave * 32;
  floatx4 oacc[2][8] = {};
  for (int jb = 0; jb < 4; ++jb) {
    floatx4 sacc[2][4] = {};
#pragma unroll
    for (int kc = 0; kc < 4; ++kc) {
      bf16x8 qf[2], kf[4];
#pragma unroll
      for (int mt = 0; mt < 2; ++mt)
        qf[mt] = *(const bf16x8*)&qkvb[(long)(b * 256 + iw + mt * 16 + l16) * 12288 +
                                       h * 384 + kc * 32 + quad * 8];
#pragma unroll
      for (int nt = 0; nt < 4; ++nt)
        kf[nt] = *(const bf16x8*)&qkvb[(long)(b * 256 + jb * 64 + nt * 16 + l16) * 12288 +
                                       h * 384 + 128 + kc * 32 + quad * 8];
#pragma unroll
      for (int mt = 0; mt < 2; ++mt)
#pragma unroll
        for (int nt = 0; nt < 4; ++nt)
          sacc[mt][nt] = MFMA16(qf[mt], kf[nt], sacc[mt][nt]);
    }
#pragma unroll
    for (int mt = 0; mt < 2; ++mt)
#pragma unroll
      for (int nt = 0; nt < 4; ++nt)
#pragma unroll
        for (int r = 0; r < 4; ++r) {
          const int i = iw + mt * 16 + quad * 4 + r;
          const int j = jb * 64 + nt * 16 + l16;
          const int diff = i - j;
          const float v = (diff >= 0) ? sacc[mt][nt][r] * ddt[diff] : 0.f;
          sbuf[wave][mt * 16 + quad * 4 + r][nt * 16 + l16] = (bf16)v;
        }
    __syncthreads();
#pragma unroll
    for (int kc2 = 0; kc2 < 2; ++kc2) {
      bf16x8 sf[2];
#pragma unroll
      for (int mt = 0; mt < 2; ++mt)
        sf[mt] = *(const bf16x8*)&sbuf[wave][mt * 16 + l16][kc2 * 32 + quad * 8];
#pragma unroll
      for (int et = 0; et < 8; ++et) {
        bf16x8 vf = *(const bf16x8*)&vT[((long)h * 128 + et * 16 + l16) * 4096 +
                                        b * 256 + jb * 64 + kc2 * 32 + quad * 8];
#pragma unroll
        for (int mt = 0; mt < 2; ++mt)
          oacc[mt][et] = MFMA16(sf[mt], vf, oacc[mt][et]);
      }
    }
    __syncthreads();
  }
#pragma unroll
  for (int kc = 0; kc < 4; ++kc) {
    bf16x8 qf[2];
#pragma unroll
    for (int mt = 0; mt < 2; ++mt) {
      bf16x8 q8 = *(const bf16x8*)&qkvb[(long)(b * 256 + iw + mt * 16 + l16) * 12288 +
                                        h * 384 + kc * 32 + quad * 8];
      const float qd = ddt[iw + mt * 16 + l16 + 1];
      bf16x8 qq;
#pragma unroll
      for (int j = 0; j < 8; ++j) qq[j] = (bf16)((float)q8[j] * qd);
      qf[mt] = qq;
    }
#pragma unroll
    for (int et = 0; et < 8; ++et) {
      bf16x8 kvf = *(const bf16x8*)&ST[(((long)h * 16 + b) * 128 + et * 16 + l16) * 128 +
                                       kc * 32 + quad * 8];
#pragma unroll
      for (int mt = 0; mt < 2; ++mt)
        oacc[mt][et] = MFMA16(qf[mt], kvf, oacc[mt][et]);
    }
  }
#pragma unroll
  for (int mt = 0; mt < 2; ++mt)
#pragma unroll
    for (int et = 0; et < 8; ++et)
#pragma unroll
      for (int r = 0; r < 4; ++r) {
        const int t = b * 256 + iw + mt * 16 + quad * 4 + r;
        const int e = et * 16 + l16;
        hidden[(long)t * 4096 + h * 128 + e] = oacc[mt][et][r];
      }
}

// ---------------------------------------------------------------------------
// RMSNorm * norm_weight * gate -> bf16
// ---------------------------------------------------------------------------
__global__ __launch_bounds__(256) void rms_gate(const float* __restrict__ hidden,
                                                const bf16* __restrict__ gateb,
                                                const float* __restrict__ nw,
                                                bf16* __restrict__ afinal) {
  const int t = blockIdx.x, tid = threadIdx.x;
  const float* rowp = hidden + (long)t * 4096;
  float ss = 0.f;
  float4 hv[4];
#pragma unroll
  for (int i = 0; i < 4; ++i) {
    hv[i] = ((const float4*)rowp)[tid + i * 256];
    ss += hv[i].x * hv[i].x + hv[i].y * hv[i].y + hv[i].z * hv[i].z + hv[i].w * hv[i].w;
  }
#pragma unroll
  for (int off = 32; off > 0; off >>= 1) ss += __shfl_down(ss, off);
  __shared__ float red[4];
  if ((tid & 63) == 0) red[tid >> 6] = ss;
  __syncthreads();
  const float tot = red[0] + red[1] + red[2] + red[3];
  const float rs = rsqrtf(tot * (1.f / 4096.f) + 1e-5f);
#pragma unroll
  for (int i = 0; i < 4; ++i) {
    const int c = (tid + i * 256) * 4;
    bf16x4 g = *(const bf16x4*)&gateb[(long)t * 4096 + c];
    float4 w = *(const float4*)&nw[c];
    bf16x4 o;
    o[0] = (bf16)(hv[i].x * rs * w.x * (float)g[0]);
    o[1] = (bf16)(hv[i].y * rs * w.y * (float)g[1]);
    o[2] = (bf16)(hv[i].z * rs * w.z * (float)g[2]);
    o[3] = (bf16)(hv[i].w * rs * w.w * (float)g[3]);
    *(bf16x4*)&afinal[(long)t * 4096 + c] = o;
  }
}

// ---------------------------------------------------------------------------
extern "C" void kernel_launch(void* const* d_in, const int* in_sizes, int n_in,
                              void* d_out, int out_size, void* d_ws, size_t ws_size,
                              hipStream_t stream) {
  (void)in_sizes; (void)n_in; (void)out_size;
  const float* x      = (const float*)d_in[0];
  const float* w_qkv  = (const float*)d_in[1];
  const float* w_gate = (const float*)d_in[2];
  const float* w_out  = (const float*)d_in[3];
  const float* nw     = (const float*)d_in[4];
  const float* kvc    = (const float*)d_in[5];
  const float* slope  = (const float*)d_in[6];
  float* out = (float*)d_out;

  const size_t MB = 1024 * 1024;
  char* base = (char*)d_ws;
  // 384 MB total with aliasing (stream order guarantees safety):
  bf16* qkvb   = (bf16*)(base + 0 * MB);     // 96 MB,  live steps 2..7
  bf16* kT     = (bf16*)(base + 96 * MB);    // 32 MB
  bf16* vT     = (bf16*)(base + 128 * MB);   // 32 MB
  bf16* wob    = (bf16*)(base + 160 * MB);   // 32 MB, live 1..9
  bf16* gateb  = (bf16*)(base + 192 * MB);   // 32 MB, live 3..8
  bf16* xb     = (bf16*)(base + 224 * MB);   // 32 MB, live 1..3
  bf16* afinal = (bf16*)(base + 224 * MB);   // aliases xb (live 8..9)
  bf16* wb     = (bf16*)(base + 256 * MB);   // 128 MB, live 1..3
  float* MT    = (float*)(base + 256 * MB);  // aliases wb (live 5..6)
  bf16* ST     = (bf16*)(base + 288 * MB);   // aliases wb (live 6..7)
  float* hidden= (float*)(base + 304 * MB);  // aliases wb (live 7..8), 64 MB
  if (ws_size < 384 * MB) return;  // clean fail -> visible as absmax blowup

  const long nx = 4096L * 4096, nqkv = 12288L * 4096;
  // 1) fp32 -> bf16 converts
  cvt_bf16<<<dim3((int)(nx / 2048)), 256, 0, stream>>>(x, xb, nx);
  cvt_bf16<<<dim3((int)(nqkv / 2048)), 256, 0, stream>>>(w_qkv, wb, nqkv);
  cvt_bf16<<<dim3((int)(nx / 2048)), 256, 0, stream>>>(w_gate, wb + nqkv, nx);
  cvt_bf16<<<dim3((int)(nx / 2048)), 256, 0, stream>>>(w_out, wob, nx);
  // 2) qkv = silu(x @ w_qkv^T), bf16   (M=4096 -> 16 row-tiles, N=12288 -> 48)
  gemm256<0><<<dim3(16 * 48), 512, 0, stream>>>(xb, wb, qkvb, 12288, 4096);
  // 3) gate = sigmoid(x @ w_gate^T), bf16
  gemm256<1><<<dim3(16 * 16), 512, 0, stream>>>(xb, wb + nqkv, gateb, 4096, 4096);
  // 4) k^T, v^T per head
  transpose_kv<<<dim3(64, 4, 32), 256, 0, stream>>>(qkvb, kT, vT);
  // 5) per-block decayed KV contributions
  kv_blocks<<<dim3(16, 32), 256, 0, stream>>>(kT, vT, slope, MT);
  // 6) sequential-in-b scan -> per-block KV states
  kv_scan<<<dim3(2048), 256, 0, stream>>>(MT, kvc, slope, ST);
  // 7) attention outputs -> hidden
  attn_out<<<dim3(16, 32), 512, 0, stream>>>(qkvb, vT, ST, slope, hidden);
  // 8) RMSNorm * nw * gate -> bf16
  rms_gate<<<dim3(4096), 256, 0, stream>>>(hidden, gateb, nw, afinal);
  // 9) out = afinal @ w_out^T, fp32
  gemm256<2><<<dim3(16 * 16), 512, 0, stream>>>(afinal, wob, out, 4096, 4096);
}

// Round 2
// 1371.474 us; speedup vs baseline: 1.2040x; 1.0003x over previous
//
#include <hip/hip_runtime.h>

typedef __bf16 bf16;
typedef __bf16 bf16x8 __attribute__((ext_vector_type(8)));
typedef __bf16 bf16x4 __attribute__((ext_vector_type(4)));
typedef float floatx4 __attribute__((ext_vector_type(4)));

#define MFMA16(a, b, c) __builtin_amdgcn_mfma_f32_16x16x32_bf16(a, b, c, 0, 0, 0)

// async global->LDS, 16 bytes/lane, dest = wave-uniform base + lane*16
#define GLOAD_LDS16(g, l)                                          \
  __builtin_amdgcn_global_load_lds(                                \
      (const __attribute__((address_space(1))) void*)(g),          \
      (__attribute__((address_space(3))) void*)(l), 16, 0, 0)

#define BAR() __builtin_amdgcn_s_barrier()
#define SCHED0() __builtin_amdgcn_sched_barrier(0)
#define LGKM0()                                        \
  do {                                                 \
    asm volatile("s_waitcnt lgkmcnt(0)" ::: "memory"); \
    __builtin_amdgcn_sched_barrier(0);                 \
  } while (0)
#define VM6() asm volatile("s_waitcnt vmcnt(6)" ::: "memory")

#define MFMA_PHASE(HM, HN, BB)                                            \
  do {                                                                    \
    __builtin_amdgcn_s_setprio(1);                                        \
    _Pragma("unroll") for (int kk = 0; kk < 2; ++kk)                      \
        _Pragma("unroll") for (int mf = 0; mf < 4; ++mf)                  \
            _Pragma("unroll") for (int nf = 0; nf < 2; ++nf)              \
                acc[HM][HN][mf][nf] =                                     \
        MFMA16(af[kk][mf], BB[kk][nf], acc[HM][HN][mf][nf]);              \
    __builtin_amdgcn_s_setprio(0);                                        \
  } while (0)

// ---------------------------------------------------------------------------
// fp32 -> bf16 elementwise convert (8 elems/thread)
// ---------------------------------------------------------------------------
__global__ __launch_bounds__(256) void cvt_bf16(const float* __restrict__ src,
                                                bf16* __restrict__ dst, long n) {
  const long i = ((long)blockIdx.x * 256 + threadIdx.x) * 8;
  if (i >= n) return;
  float4 a = *(const float4*)&src[i];
  float4 b = *(const float4*)&src[i + 4];
  bf16x8 o = {(bf16)a.x, (bf16)a.y, (bf16)a.z, (bf16)a.w,
              (bf16)b.x, (bf16)b.y, (bf16)b.z, (bf16)b.w};
  *(bf16x8*)&dst[i] = o;
}

// ---------------------------------------------------------------------------
// 256x256-tile 8-phase NT GEMM (m201 structure): C[m][n] = epi(sum_k A[m][k]*B[n][k])
// 512 threads = 8 waves (2M x 4N). BK=64, double-buffered 128 KiB LDS.
// 2-bit XOR swizzle: col_elem ^= ((row>>2)&3)<<4. Row stride = 128 B = 32 banks,
// so only the column picks the bank; base fragment cols use 4 of 8 16B-slots.
// Bit4 permutes within a K-half, bit5 crosses K-halves -> each ds_read_b128
// spreads 8 lanes on each of 8 slots = all 32 banks = conflict-free.
// Realized as linear global_load_lds dest + inverse-swizzled global source
// (row bit2 = lane b5, row bit3 = wave b0) + swizzled ds_read (row bits = l16 b2..b3).
// Counted vmcnt(6) at phases 3/7 only (3 half-tiles in flight).
// Half-tile retirement: A-h0 read ph0 -> staged ph1 ; B-h0 read ph0 -> staged ph2 ;
//   B-h1 read ph1 -> staged ph3 ; A-h1 read ph2 -> staged ph4 (next buf: +4).
// EPI: 0 = silu -> bf16, 1 = sigmoid -> bf16, 2 = identity -> fp32
// ---------------------------------------------------------------------------
template <int EPI>
__global__ __launch_bounds__(512, 2) void gemm256(const bf16* __restrict__ A,
                                                  const bf16* __restrict__ B,
                                                  void* __restrict__ Cv,
                                                  int N, int K) {
  __shared__ bf16 AS[2][256 * 64];
  __shared__ bf16 BS[2][256 * 64];
  const int tid = threadIdx.x;
  const int wave = tid >> 6, lane = tid & 63;
  const int quad = lane >> 4, l16 = lane & 15;
  const int wm = wave >> 2, wn = wave & 3;
  // read-side col XOR (elems): ((l16>>2)&3)<<4
  const int cswz = (l16 & 12) << 2;
  // stage-side source col (elems): slot ^ (row-bit2 = lane b5, row-bit3 = wave b0)
  const int gc = ((lane & 7) * 8) ^
                 (((((wave & 1) << 1) | ((lane >> 5) & 1))) << 4);

  // bijective XCD-aware block swizzle (m204 variant)
  int wg = blockIdx.x;
  {
    const int nwg = gridDim.x;
    const int q = nwg >> 3, r = nwg & 7, xcd = wg & 7, idx = wg >> 3;
    wg = (xcd < r ? xcd * (q + 1) : r * (q + 1) + (xcd - r) * q) + idx;
  }
  const int nbn = N >> 8;
  const int bm = wg / nbn, bn = wg - bm * nbn;

  const bf16* gA = A + (long)(bm * 256) * K;
  const bf16* gB = B + (long)(bn * 256) * K;

  auto stA = [&](int buf, int h, int kt) {
#pragma unroll
    for (int j = 0; j < 2; ++j) {
      const int rb = h * 128 + j * 64 + wave * 8;  // wave-uniform LDS row base
      GLOAD_LDS16(gA + (long)(rb + (lane >> 3)) * K + kt * 64 + gc,
                  &AS[buf][rb * 64]);
    }
  };
  auto stB = [&](int buf, int h, int kt) {
#pragma unroll
    for (int j = 0; j < 2; ++j) {
      const int rb = h * 128 + j * 64 + wave * 8;
      GLOAD_LDS16(gB + (long)(rb + (lane >> 3)) * K + kt * 64 + gc,
                  &BS[buf][rb * 64]);
    }
  };

  bf16x8 af[2][4], b0[2][2], b1[2][2];
  floatx4 acc[2][2][4][2] = {};

  auto rdA = [&](int buf, int hm) {
#pragma unroll
    for (int kk = 0; kk < 2; ++kk)
#pragma unroll
      for (int mf = 0; mf < 4; ++mf) {
        const int R = hm * 128 + wm * 64 + mf * 16 + l16;
        af[kk][mf] =
            *(const bf16x8*)&AS[buf][R * 64 + ((kk * 32 + quad * 8) ^ cswz)];
      }
  };
  auto rdB = [&](int buf, int hn, bf16x8 (&bb)[2][2]) {
#pragma unroll
    for (int kk = 0; kk < 2; ++kk)
#pragma unroll
      for (int nf = 0; nf < 2; ++nf) {
        const int R = hn * 128 + wn * 32 + nf * 16 + l16;
        bb[kk][nf] =
            *(const bf16x8*)&BS[buf][R * 64 + ((kk * 32 + quad * 8) ^ cswz)];
      }
  };

  const int NT = K >> 6;   // number of K=64 tiles
  const int NI = NT >> 1;  // 2 tiles per iteration

  // prologue: tile0 {A0,A1,B0,B1} -> buf0 ; tile1 {A0,B0,B1} -> buf1 (A1 at ph0)
  stA(0, 0, 0); stA(0, 1, 0); stB(0, 0, 0); stB(0, 1, 0);
  stA(1, 0, 1); stB(1, 0, 1); stB(1, 1, 1);
  VM6();  // oldest 8 loads = tile0 complete; 6 in flight
  BAR();

  for (int it = 0; it < NI; ++it) {
    const int t1 = 2 * it + 1;
    const int t2 = (2 * it + 2 < NT) ? 2 * it + 2 : NT - 1;  // clamped tail restage
    const int t3 = (2 * it + 3 < NT) ? 2 * it + 3 : NT - 1;
    // ph0: quadrant (0,0) of tile 2it (buf0); finish tile 2it+1 staging
    rdA(0, 0); rdB(0, 0, b0);
    stA(1, 1, t1);
    SCHED0(); BAR(); LGKM0();
    MFMA_PHASE(0, 0, b0);
    BAR();
    // ph1: (0,1); stage next-buf0 A-h0
    rdB(0, 1, b1);
    stA(0, 0, t2);
    SCHED0(); BAR(); LGKM0();
    MFMA_PHASE(0, 1, b1);
    BAR();
    // ph2: (1,0); stage next-buf0 B-h0
    rdA(0, 1);
    stB(0, 0, t2);
    SCHED0(); BAR(); LGKM0();
    MFMA_PHASE(1, 0, b0);
    BAR();
    // ph3: (1,1); stage next-buf0 B-h1; counted wait -> buf1 (tile 2it+1) complete
    stB(0, 1, t2);
    VM6(); SCHED0(); BAR(); SCHED0();
    MFMA_PHASE(1, 1, b1);
    BAR();
    // ph4: quadrant (0,0) of tile 2it+1 (buf1); stage next-buf0 A-h1
    rdA(1, 0); rdB(1, 0, b0);
    stA(0, 1, t2);
    SCHED0(); BAR(); LGKM0();
    MFMA_PHASE(0, 0, b0);
    BAR();
    // ph5: (0,1); stage next-buf1 A-h0
    rdB(1, 1, b1);
    stA(1, 0, t3);
    SCHED0(); BAR(); LGKM0();
    MFMA_PHASE(0, 1, b1);
    BAR();
    // ph6: (1,0); stage next-buf1 B-h0
    rdA(1, 1);
    stB(1, 0, t3);
    SCHED0(); BAR(); LGKM0();
    MFMA_PHASE(1, 0, b0);
    BAR();
    // ph7: (1,1); stage next-buf1 B-h1; counted wait -> next buf0 complete
    stB(1, 1, t3);
    VM6(); SCHED0(); BAR(); SCHED0();
    MFMA_PHASE(1, 1, b1);
    BAR();
  }

#pragma unroll
  for (int hm = 0; hm < 2; ++hm)
#pragma unroll
    for (int hn = 0; hn < 2; ++hn)
#pragma unroll
      for (int mf = 0; mf < 4; ++mf)
#pragma unroll
        for (int nf = 0; nf < 2; ++nf)
#pragma unroll
          for (int r = 0; r < 4; ++r) {
            const int row = bm * 256 + hm * 128 + wm * 64 + mf * 16 + quad * 4 + r;
            const int col = bn * 256 + hn * 128 + wn * 32 + nf * 16 + l16;
            const float v = acc[hm][hn][mf][nf][r];
            if constexpr (EPI == 0) {
              ((bf16*)Cv)[(long)row * N + col] = (bf16)(v / (1.f + __expf(-v)));
            } else if constexpr (EPI == 1) {
              ((bf16*)Cv)[(long)row * N + col] = (bf16)(1.f / (1.f + __expf(-v)));
            } else {
              ((float*)Cv)[(long)row * N + col] = v;
            }
          }
}

// ---------------------------------------------------------------------------
// Build kT[h][d][t] and vT[h][e][t] (bf16) from qkvb[t][h*384 + {128+d, 256+e}]
// ---------------------------------------------------------------------------
__global__ __launch_bounds__(256) void transpose_kv(const bf16* __restrict__ qkvb,
                                                    bf16* __restrict__ kT,
                                                    bf16* __restrict__ vT) {
  __shared__ bf16 tile[64][72];
  const int tid = threadIdx.x;
  const int t0 = blockIdx.x * 64;
  const int qz = blockIdx.y;
  const int h = blockIdx.z;
  const int srccol = h * 384 + 128 + (qz >> 1) * 128 + (qz & 1) * 64;
  const int row = tid >> 2, cb = (tid & 3) * 16;
#pragma unroll
  for (int i = 0; i < 2; ++i)
    *(bf16x8*)&tile[row][cb + i * 8] =
        *(const bf16x8*)&qkvb[(long)(t0 + row) * 12288 + srccol + cb + i * 8];
  __syncthreads();
  bf16* dst = (qz >= 2) ? vT : kT;
  const int ch = (qz & 1) * 64 + (tid >> 2);
#pragma unroll
  for (int i = 0; i < 2; ++i) {
    bf16x8 v;
#pragma unroll
    for (int j = 0; j < 8; ++j) v[j] = tile[cb + i * 8 + j][tid >> 2];
    *(bf16x8*)&dst[((long)h * 128 + ch) * 4096 + t0 + cb + i * 8] = v;
  }
}

// ---------------------------------------------------------------------------
// MT[h][b][e][d] = sum_i v[i][e] * (exp(-s*(255-i)) * k[i][d]),  fp32
// ---------------------------------------------------------------------------
__global__ __launch_bounds__(256) void kv_blocks(const bf16* __restrict__ kT,
                                                 const bf16* __restrict__ vT,
                                                 const float* __restrict__ slope,
                                                 float* __restrict__ MT) {
  __shared__ float kdec[256];
  const int tid = threadIdx.x;
  const int b = blockIdx.x, h = blockIdx.y;
  const float s = slope[h];
  if (tid < 256) kdec[tid] = __expf(-s * (float)(255 - tid));
  __syncthreads();
  const int wave = tid >> 6, lane = tid & 63;
  const int quad = lane >> 4, l16 = lane & 15;
  const int we = (wave & 1) * 64, wd = (wave >> 1) * 64;
  floatx4 acc[4][4] = {};
  for (int kc = 0; kc < 8; ++kc) {
    const int ioff = kc * 32 + quad * 8;
    bf16x8 af[4], bfr[4];
#pragma unroll
    for (int mt = 0; mt < 4; ++mt)
      af[mt] = *(const bf16x8*)&vT[((long)h * 128 + we + mt * 16 + l16) * 4096 +
                                   b * 256 + ioff];
#pragma unroll
    for (int nt = 0; nt < 4; ++nt) {
      bf16x8 k8 = *(const bf16x8*)&kT[((long)h * 128 + wd + nt * 16 + l16) * 4096 +
                                      b * 256 + ioff];
      bf16x8 kb;
#pragma unroll
      for (int j = 0; j < 8; ++j) kb[j] = (bf16)((float)k8[j] * kdec[ioff + j]);
      bfr[nt] = kb;
    }
#pragma unroll
    for (int mt = 0; mt < 4; ++mt)
#pragma unroll
      for (int nt = 0; nt < 4; ++nt)
        acc[mt][nt] = MFMA16(af[mt], bfr[nt], acc[mt][nt]);
  }
#pragma unroll
  for (int mt = 0; mt < 4; ++mt)
#pragma unroll
    for (int nt = 0; nt < 4; ++nt)
#pragma unroll
      for (int r = 0; r < 4; ++r) {
        const int e = we + mt * 16 + quad * 4 + r;
        const int d = wd + nt * 16 + l16;
        MT[(((long)h * 16 + b) * 128 + e) * 128 + d] = acc[mt][nt][r];
      }
}

// ---------------------------------------------------------------------------
// ST[h][b][e][d] = KV_b[d][e] (bf16); KV_0 = kv_cache, KV_{b+1}=bd*KV_b + M_b
// ---------------------------------------------------------------------------
__global__ __launch_bounds__(256) void kv_scan(const float* __restrict__ MT,
                                               const float* __restrict__ kvc,
                                               const float* __restrict__ slope,
                                               bf16* __restrict__ ST) {
  const long idx = (long)blockIdx.x * 256 + threadIdx.x;
  const int d = idx & 127;
  const int e = (int)((idx >> 7) & 127);
  const int h = (int)(idx >> 14);
  const float s = slope[h];
  const float bd = __expf(-s * 256.f);
  float kv = kvc[((long)h * 128 + d) * 128 + e];
#pragma unroll
  for (int b = 0; b < 16; ++b) {
    const long o = (((long)h * 16 + b) * 128 + e) * 128 + d;
    ST[o] = (bf16)kv;
    kv = bd * kv + MT[o];
  }
}

// ---------------------------------------------------------------------------
// Per-(head,block) attention output -> hidden fp32 [t][h*128+e]
// ---------------------------------------------------------------------------
__global__ __launch_bounds__(512) void attn_out(const bf16* __restrict__ qkvb,
                                                const bf16* __restrict__ vT,
                                                const bf16* __restrict__ ST,
                                                const float* __restrict__ slope,
                                                float* __restrict__ hidden) {
  __shared__ float ddt[257];
  __shared__ bf16 sbuf[8][32][72];
  const int tid = threadIdx.x;
  const int b = blockIdx.x, h = blockIdx.y;
  const float s = slope[h];
  if (tid < 257) ddt[tid] = __expf(-s * (float)tid);
  __syncthreads();
  const int wave = tid >> 6, lane = tid & 63;
  const int quad = lane >> 4, l16 = lane & 15;
  const int iw = wave * 32;
  floatx4 oacc[2][8] = {};
  for (int jb = 0; jb < 4; ++jb) {
    floatx4 sacc[2][4] = {};
#pragma unroll
    for (int kc = 0; kc < 4; ++kc) {
      bf16x8 qf[2], kf[4];
#pragma unroll
      for (int mt = 0; mt < 2; ++mt)
        qf[mt] = *(const bf16x8*)&qkvb[(long)(b * 256 + iw + mt * 16 + l16) * 12288 +
                                       h * 384 + kc * 32 + quad * 8];
#pragma unroll
      for (int nt = 0; nt < 4; ++nt)
        kf[nt] = *(const bf16x8*)&qkvb[(long)(b * 256 + jb * 64 + nt * 16 + l16) * 12288 +
                                       h * 384 + 128 + kc * 32 + quad * 8];
#pragma unroll
      for (int mt = 0; mt < 2; ++mt)
#pragma unroll
        for (int nt = 0; nt < 4; ++nt)
          sacc[mt][nt] = MFMA16(qf[mt], kf[nt], sacc[mt][nt]);
    }
#pragma unroll
    for (int mt = 0; mt < 2; ++mt)
#pragma unroll
      for (int nt = 0; nt < 4; ++nt)
#pragma unroll
        for (int r = 0; r < 4; ++r) {
          const int i = iw + mt * 16 + quad * 4 + r;
          const int j = jb * 64 + nt * 16 + l16;
          const int diff = i - j;
          const float v = (diff >= 0) ? sacc[mt][nt][r] * ddt[diff] : 0.f;
          sbuf[wave][mt * 16 + quad * 4 + r][nt * 16 + l16] = (bf16)v;
        }
    __syncthreads();
#pragma unroll
    for (int kc2 = 0; kc2 < 2; ++kc2) {
      bf16x8 sf[2];
#pragma unroll
      for (int mt = 0; mt < 2; ++mt)
        sf[mt] = *(const bf16x8*)&sbuf[wave][mt * 16 + l16][kc2 * 32 + quad * 8];
#pragma unroll
      for (int et = 0; et < 8; ++et) {
        bf16x8 vf = *(const bf16x8*)&vT[((long)h * 128 + et * 16 + l16) * 4096 +
                                        b * 256 + jb * 64 + kc2 * 32 + quad * 8];
#pragma unroll
        for (int mt = 0; mt < 2; ++mt)
          oacc[mt][et] = MFMA16(sf[mt], vf, oacc[mt][et]);
      }
    }
    __syncthreads();
  }
#pragma unroll
  for (int kc = 0; kc < 4; ++kc) {
    bf16x8 qf[2];
#pragma unroll
    for (int mt = 0; mt < 2; ++mt) {
      bf16x8 q8 = *(const bf16x8*)&qkvb[(long)(b * 256 + iw + mt * 16 + l16) * 12288 +
                                        h * 384 + kc * 32 + quad * 8];
      const float qd = ddt[iw + mt * 16 + l16 + 1];
      bf16x8 qq;
#pragma unroll
      for (int j = 0; j < 8; ++j) qq[j] = (bf16)((float)q8[j] * qd);
      qf[mt] = qq;
    }
#pragma unroll
    for (int et = 0; et < 8; ++et) {
      bf16x8 kvf = *(const bf16x8*)&ST[(((long)h * 16 + b) * 128 + et * 16 + l16) * 128 +
                                       kc * 32 + quad * 8];
#pragma unroll
      for (int mt = 0; mt < 2; ++mt)
        oacc[mt][et] = MFMA16(qf[mt], kvf, oacc[mt][et]);
    }
  }
#pragma unroll
  for (int mt = 0; mt < 2; ++mt)
#pragma unroll
    for (int et = 0; et < 8; ++et)
#pragma unroll
      for (int r = 0; r < 4; ++r) {
        const int t = b * 256 + iw + mt * 16 + quad * 4 + r;
        const int e = et * 16 + l16;
        hidden[(long)t * 4096 + h * 128 + e] = oacc[mt][et][r];
      }
}

// ---------------------------------------------------------------------------
// RMSNorm * norm_weight * gate -> bf16
// ---------------------------------------------------------------------------
__global__ __launch_bounds__(256) void rms_gate(const float* __restrict__ hidden,
                                                const bf16* __restrict__ gateb,
                                                const float* __restrict__ nw,
                                                bf16* __restrict__ afinal) {
  const int t = blockIdx.x, tid = threadIdx.x;
  const float* rowp = hidden + (long)t * 4096;
  float ss = 0.f;
  float4 hv[4];
#pragma unroll
  for (int i = 0; i < 4; ++i) {
    hv[i] = ((const float4*)rowp)[tid + i * 256];
    ss += hv[i].x * hv[i].x + hv[i].y * hv[i].y + hv[i].z * hv[i].z + hv[i].w * hv[i].w;
  }
#pragma unroll
  for (int off = 32; off > 0; off >>= 1) ss += __shfl_down(ss, off);
  __shared__ float red[4];
  if ((tid & 63) == 0) red[tid >> 6] = ss;
  __syncthreads();
  const float tot = red[0] + red[1] + red[2] + red[3];
  const float rs = rsqrtf(tot * (1.f / 4096.f) + 1e-5f);
#pragma unroll
  for (int i = 0; i < 4; ++i) {
    const int c = (tid + i * 256) * 4;
    bf16x4 g = *(const bf16x4*)&gateb[(long)t * 4096 + c];
    float4 w = *(const float4*)&nw[c];
    bf16x4 o;
    o[0] = (bf16)(hv[i].x * rs * w.x * (float)g[0]);
    o[1] = (bf16)(hv[i].y * rs * w.y * (float)g[1]);
    o[2] = (bf16)(hv[i].z * rs * w.z * (float)g[2]);
    o[3] = (bf16)(hv[i].w * rs * w.w * (float)g[3]);
    *(bf16x4*)&afinal[(long)t * 4096 + c] = o;
  }
}

// ---------------------------------------------------------------------------
extern "C" void kernel_launch(void* const* d_in, const int* in_sizes, int n_in,
                              void* d_out, int out_size, void* d_ws, size_t ws_size,
                              hipStream_t stream) {
  (void)in_sizes; (void)n_in; (void)out_size;
  const float* x      = (const float*)d_in[0];
  const float* w_qkv  = (const float*)d_in[1];
  const float* w_gate = (const float*)d_in[2];
  const float* w_out  = (const float*)d_in[3];
  const float* nw     = (const float*)d_in[4];
  const float* kvc    = (const float*)d_in[5];
  const float* slope  = (const float*)d_in[6];
  float* out = (float*)d_out;

  const size_t MB = 1024 * 1024;
  char* base = (char*)d_ws;
  // 384 MB total with aliasing (stream order guarantees safety):
  bf16* qkvb   = (bf16*)(base + 0 * MB);     // 96 MB,  live steps 2..7
  bf16* kT     = (bf16*)(base + 96 * MB);    // 32 MB
  bf16* vT     = (bf16*)(base + 128 * MB);   // 32 MB
  bf16* wob    = (bf16*)(base + 160 * MB);   // 32 MB, live 1..9
  bf16* gateb  = (bf16*)(base + 192 * MB);   // 32 MB, live 3..8
  bf16* xb     = (bf16*)(base + 224 * MB);   // 32 MB, live 1..3
  bf16* afinal = (bf16*)(base + 224 * MB);   // aliases xb (live 8..9)
  bf16* wb     = (bf16*)(base + 256 * MB);   // 128 MB, live 1..3
  float* MT    = (float*)(base + 256 * MB);  // aliases wb (live 5..6)
  bf16* ST     = (bf16*)(base + 288 * MB);   // aliases wb (live 6..7)
  float* hidden= (float*)(base + 304 * MB);  // aliases wb (live 7..8), 64 MB
  if (ws_size < 384 * MB) return;  // clean fail -> visible as absmax blowup

  const long nx = 4096L * 4096, nqkv = 12288L * 4096;
  // 1) fp32 -> bf16 converts
  cvt_bf16<<<dim3((int)(nx / 2048)), 256, 0, stream>>>(x, xb, nx);
  cvt_bf16<<<dim3((int)(nqkv / 2048)), 256, 0, stream>>>(w_qkv, wb, nqkv);
  cvt_bf16<<<dim3((int)(nx / 2048)), 256, 0, stream>>>(w_gate, wb + nqkv, nx);
  cvt_bf16<<<dim3((int)(nx / 2048)), 256, 0, stream>>>(w_out, wob, nx);
  // 2) qkv = silu(x @ w_qkv^T), bf16   (M=4096 -> 16 row-tiles, N=12288 -> 48)
  gemm256<0><<<dim3(16 * 48), 512, 0, stream>>>(xb, wb, qkvb, 12288, 4096);
  // 3) gate = sigmoid(x @ w_gate^T), bf16
  gemm256<1><<<dim3(16 * 16), 512, 0, stream>>>(xb, wb + nqkv, gateb, 4096, 4096);
  // 4) k^T, v^T per head
  transpose_kv<<<dim3(64, 4, 32), 256, 0, stream>>>(qkvb, kT, vT);
  // 5) per-block decayed KV contributions
  kv_blocks<<<dim3(16, 32), 256, 0, stream>>>(kT, vT, slope, MT);
  // 6) sequential-in-b scan -> per-block KV states
  kv_scan<<<dim3(2048), 256, 0, stream>>>(MT, kvc, slope, ST);
  // 7) attention outputs -> hidden
  attn_out<<<dim3(16, 32), 512, 0, stream>>>(qkvb, vT, ST, slope, hidden);
  // 8) RMSNorm * nw * gate -> bf16
  rms_gate<<<dim3(4096), 256, 0, stream>>>(hidden, gateb, nw, afinal);
  // 9) out = afinal @ w_out^T, fp32
  gemm256<2><<<dim3(16 * 16), 512, 0, stream>>>(afinal, wob, out, 4096, 4096);
}

// Round 3
// 1276.380 us; speedup vs baseline: 1.2937x; 1.0745x over previous
//
#include <hip/hip_runtime.h>

typedef __bf16 bf16;
typedef __bf16 bf16x8 __attribute__((ext_vector_type(8)));
typedef __bf16 bf16x4 __attribute__((ext_vector_type(4)));
typedef float floatx4 __attribute__((ext_vector_type(4)));

#define MFMA16(a, b, c) __builtin_amdgcn_mfma_f32_16x16x32_bf16(a, b, c, 0, 0, 0)

// async global->LDS, 16 bytes/lane, dest = wave-uniform base + lane*16
#define GLOAD_LDS16(g, l)                                          \
  __builtin_amdgcn_global_load_lds(                                \
      (const __attribute__((address_space(1))) void*)(g),          \
      (__attribute__((address_space(3))) void*)(l), 16, 0, 0)

#define BAR() __builtin_amdgcn_s_barrier()
#define SCHED0() __builtin_amdgcn_sched_barrier(0)
#define VM6() asm volatile("s_waitcnt vmcnt(6)" ::: "memory")

// ---------------------------------------------------------------------------
// fp32 -> bf16 elementwise convert (8 elems/thread)
// ---------------------------------------------------------------------------
__global__ __launch_bounds__(256) void cvt_bf16(const float* __restrict__ src,
                                                bf16* __restrict__ dst, long n) {
  const long i = ((long)blockIdx.x * 256 + threadIdx.x) * 8;
  if (i >= n) return;
  float4 a = *(const float4*)&src[i];
  float4 b = *(const float4*)&src[i + 4];
  bf16x8 o = {(bf16)a.x, (bf16)a.y, (bf16)a.z, (bf16)a.w,
              (bf16)b.x, (bf16)b.y, (bf16)b.z, (bf16)b.w};
  *(bf16x8*)&dst[i] = o;
}

// ---------------------------------------------------------------------------
// 256x256-tile software-pipelined NT GEMM: C[m][n] = epi(sum_k A[m][k]*B[n][k])
// 512 threads = 8 waves (2M x 4N). BK=64, double-buffered 128 KiB LDS.
// 8 windows per 2 K-tiles; each window (ONE barrier):
//   STAGE (2 gloads) -> MFMA(16, frags read LAST window) -> READS(next window)
//   -> vmcnt(6) -> s_barrier
// Reads issue after the MFMA cluster (use-then-def: single frag sets, no
// ping-pong) and complete under the vmcnt stall + barrier + next stage.
// Cyclic schedule (verified): stage unit at window s is read at end of s+4;
// vmcnt(6) leaves stages {p-2,p-1,p} in flight and retires exactly the
// region read one window later; every read follows a (vmcnt->barrier) pair
// that published its region; stage overwrites have a 2-barrier margin.
// Read slots balanced 4/8: end-ph0 b1<-BS0h1, ph1 af<-AS0h1, ph2 b0<-BS1h0,
//   ph3 af<-AS1h0, ph4 b1<-BS1h1, ph5 af<-AS1h1, ph6 b0<-BS0h0(next),
//   ph7 af<-AS0h0(next).
// Stage slots: ph0 BS1h1<-t1, ph1 AS1h1<-t1, ph2 BS0h0<-t2, ph3 AS0h0<-t2,
//   ph4 BS0h1<-t2, ph5 AS0h1<-t2, ph6 BS1h0<-t3, ph7 AS1h0<-t3.
// EPI: 0 = silu -> bf16, 1 = sigmoid -> bf16, 2 = identity -> fp32
// ---------------------------------------------------------------------------
template <int EPI>
__global__ __launch_bounds__(512, 2) void gemm256(const bf16* __restrict__ A,
                                                  const bf16* __restrict__ B,
                                                  void* __restrict__ Cv,
                                                  int N, int K) {
  __shared__ bf16 AS[2][256 * 64];
  __shared__ bf16 BS[2][256 * 64];
  const int tid = threadIdx.x;
  const int wave = tid >> 6, lane = tid & 63;
  const int quad = lane >> 4, l16 = lane & 15;
  const int wm = wave >> 2, wn = wave & 3;
  // read-side col XOR (elems): ((l16>>2)&3)<<4  (conflict-free, verified r1/r2)
  const int cswz = (l16 & 12) << 2;
  // stage-side source col (elems): slot ^ (row-bit2 = lane b5, row-bit3 = wave b0)
  const int gc = ((lane & 7) * 8) ^
                 (((((wave & 1) << 1) | ((lane >> 5) & 1))) << 4);

  // bijective XCD-aware block swizzle (m204 variant)
  int wg = blockIdx.x;
  {
    const int nwg = gridDim.x;
    const int q = nwg >> 3, r = nwg & 7, xcd = wg & 7, idx = wg >> 3;
    wg = (xcd < r ? xcd * (q + 1) : r * (q + 1) + (xcd - r) * q) + idx;
  }
  const int nbn = N >> 8;
  const int bm = wg / nbn, bn = wg - bm * nbn;

  const bf16* gA = A + (long)(bm * 256) * K;
  const bf16* gB = B + (long)(bn * 256) * K;

  auto stA = [&](int buf, int h, int kt) {
#pragma unroll
    for (int j = 0; j < 2; ++j) {
      const int rb = h * 128 + j * 64 + wave * 8;  // wave-uniform LDS row base
      GLOAD_LDS16(gA + (long)(rb + (lane >> 3)) * K + kt * 64 + gc,
                  &AS[buf][rb * 64]);
    }
  };
  auto stB = [&](int buf, int h, int kt) {
#pragma unroll
    for (int j = 0; j < 2; ++j) {
      const int rb = h * 128 + j * 64 + wave * 8;
      GLOAD_LDS16(gB + (long)(rb + (lane >> 3)) * K + kt * 64 + gc,
                  &BS[buf][rb * 64]);
    }
  };

  bf16x8 af[2][4], b0[2][2], b1[2][2];
  floatx4 acc[2][2][4][2] = {};

  auto rdAf = [&](int buf, int hm) {
#pragma unroll
    for (int kk = 0; kk < 2; ++kk)
#pragma unroll
      for (int mf = 0; mf < 4; ++mf) {
        const int R = hm * 128 + wm * 64 + mf * 16 + l16;
        af[kk][mf] =
            *(const bf16x8*)&AS[buf][R * 64 + ((kk * 32 + quad * 8) ^ cswz)];
      }
  };
  auto rdB0 = [&](int buf) {
#pragma unroll
    for (int kk = 0; kk < 2; ++kk)
#pragma unroll
      for (int nf = 0; nf < 2; ++nf) {
        const int R = wn * 32 + nf * 16 + l16;  // B half 0
        b0[kk][nf] =
            *(const bf16x8*)&BS[buf][R * 64 + ((kk * 32 + quad * 8) ^ cswz)];
      }
  };
  auto rdB1 = [&](int buf) {
#pragma unroll
    for (int kk = 0; kk < 2; ++kk)
#pragma unroll
      for (int nf = 0; nf < 2; ++nf) {
        const int R = 128 + wn * 32 + nf * 16 + l16;  // B half 1
        b1[kk][nf] =
            *(const bf16x8*)&BS[buf][R * 64 + ((kk * 32 + quad * 8) ^ cswz)];
      }
  };

#define MFMA_Q(HM, HN, BB)                                                \
  do {                                                                    \
    __builtin_amdgcn_s_setprio(1);                                        \
    _Pragma("unroll") for (int kk = 0; kk < 2; ++kk)                      \
        _Pragma("unroll") for (int mf = 0; mf < 4; ++mf)                  \
            _Pragma("unroll") for (int nf = 0; nf < 2; ++nf)              \
                acc[HM][HN][mf][nf] =                                     \
        MFMA16(af[kk][mf], BB[kk][nf], acc[HM][HN][mf][nf]);              \
    __builtin_amdgcn_s_setprio(0);                                        \
  } while (0)

#define WINDOW(STG, HM, HN, BB, RD) \
  do {                              \
    STG;                            \
    MFMA_Q(HM, HN, BB);             \
    SCHED0();                       \
    RD;                             \
    SCHED0();                       \
    VM6();                          \
    BAR();                          \
  } while (0)

  const int NT = K >> 6;   // number of K=64 tiles
  const int NI = NT >> 1;  // 2 tiles per iteration

  // prologue: virtual windows ph2'..ph7' (stage order matters for vmcnt math)
  stB(0, 0, 0); stA(0, 0, 0); stB(0, 1, 0); stA(0, 1, 0);
  stB(1, 0, 1); stA(1, 0, 1);
  VM6();  // 12 -> 6 outstanding: retires BS0h0, AS0h0, BS0h1
  BAR();  // publish
  rdB0(0); rdAf(0, 0);  // frags for window ph0

  for (int it = 0; it < NI; ++it) {
    const int t1 = 2 * it + 1;
    const int t2 = (2 * it + 2 < NT) ? 2 * it + 2 : NT - 1;  // clamped tail
    const int t3 = (2 * it + 3 < NT) ? 2 * it + 3 : NT - 1;
    WINDOW(stB(1, 1, t1), 0, 0, b0, rdB1(0));   // ph0
    WINDOW(stA(1, 1, t1), 0, 1, b1, rdAf(0, 1));// ph1
    WINDOW(stB(0, 0, t2), 1, 0, b0, rdB0(1));   // ph2
    WINDOW(stA(0, 0, t2), 1, 1, b1, rdAf(1, 0));// ph3
    WINDOW(stB(0, 1, t2), 0, 0, b0, rdB1(1));   // ph4
    WINDOW(stA(0, 1, t2), 0, 1, b1, rdAf(1, 1));// ph5
    WINDOW(stB(1, 0, t3), 1, 0, b0, rdB0(0));   // ph6
    WINDOW(stA(1, 0, t3), 1, 1, b1, rdAf(0, 0));// ph7
  }

#pragma unroll
  for (int hm = 0; hm < 2; ++hm)
#pragma unroll
    for (int hn = 0; hn < 2; ++hn)
#pragma unroll
      for (int mf = 0; mf < 4; ++mf)
#pragma unroll
        for (int nf = 0; nf < 2; ++nf)
#pragma unroll
          for (int r = 0; r < 4; ++r) {
            const int row = bm * 256 + hm * 128 + wm * 64 + mf * 16 + quad * 4 + r;
            const int col = bn * 256 + hn * 128 + wn * 32 + nf * 16 + l16;
            const float v = acc[hm][hn][mf][nf][r];
            if constexpr (EPI == 0) {
              ((bf16*)Cv)[(long)row * N + col] = (bf16)(v / (1.f + __expf(-v)));
            } else if constexpr (EPI == 1) {
              ((bf16*)Cv)[(long)row * N + col] = (bf16)(1.f / (1.f + __expf(-v)));
            } else {
              ((float*)Cv)[(long)row * N + col] = v;
            }
          }
#undef MFMA_Q
#undef WINDOW
}

// ---------------------------------------------------------------------------
// Build kT[h][d][t] and vT[h][e][t] (bf16) from qkvb[t][h*384 + {128+d, 256+e}]
// ---------------------------------------------------------------------------
__global__ __launch_bounds__(256) void transpose_kv(const bf16* __restrict__ qkvb,
                                                    bf16* __restrict__ kT,
                                                    bf16* __restrict__ vT) {
  __shared__ bf16 tile[64][72];
  const int tid = threadIdx.x;
  const int t0 = blockIdx.x * 64;
  const int qz = blockIdx.y;
  const int h = blockIdx.z;
  const int srccol = h * 384 + 128 + (qz >> 1) * 128 + (qz & 1) * 64;
  const int row = tid >> 2, cb = (tid & 3) * 16;
#pragma unroll
  for (int i = 0; i < 2; ++i)
    *(bf16x8*)&tile[row][cb + i * 8] =
        *(const bf16x8*)&qkvb[(long)(t0 + row) * 12288 + srccol + cb + i * 8];
  __syncthreads();
  bf16* dst = (qz >= 2) ? vT : kT;
  const int ch = (qz & 1) * 64 + (tid >> 2);
#pragma unroll
  for (int i = 0; i < 2; ++i) {
    bf16x8 v;
#pragma unroll
    for (int j = 0; j < 8; ++j) v[j] = tile[cb + i * 8 + j][tid >> 2];
    *(bf16x8*)&dst[((long)h * 128 + ch) * 4096 + t0 + cb + i * 8] = v;
  }
}

// ---------------------------------------------------------------------------
// MT[h][b][e][d] = sum_i v[i][e] * (exp(-s*(255-i)) * k[i][d]),  fp32
// ---------------------------------------------------------------------------
__global__ __launch_bounds__(256) void kv_blocks(const bf16* __restrict__ kT,
                                                 const bf16* __restrict__ vT,
                                                 const float* __restrict__ slope,
                                                 float* __restrict__ MT) {
  __shared__ float kdec[256];
  const int tid = threadIdx.x;
  const int b = blockIdx.x, h = blockIdx.y;
  const float s = slope[h];
  if (tid < 256) kdec[tid] = __expf(-s * (float)(255 - tid));
  __syncthreads();
  const int wave = tid >> 6, lane = tid & 63;
  const int quad = lane >> 4, l16 = lane & 15;
  const int we = (wave & 1) * 64, wd = (wave >> 1) * 64;
  floatx4 acc[4][4] = {};
  for (int kc = 0; kc < 8; ++kc) {
    const int ioff = kc * 32 + quad * 8;
    bf16x8 af[4], bfr[4];
#pragma unroll
    for (int mt = 0; mt < 4; ++mt)
      af[mt] = *(const bf16x8*)&vT[((long)h * 128 + we + mt * 16 + l16) * 4096 +
                                   b * 256 + ioff];
#pragma unroll
    for (int nt = 0; nt < 4; ++nt) {
      bf16x8 k8 = *(const bf16x8*)&kT[((long)h * 128 + wd + nt * 16 + l16) * 4096 +
                                      b * 256 + ioff];
      bf16x8 kb;
#pragma unroll
      for (int j = 0; j < 8; ++j) kb[j] = (bf16)((float)k8[j] * kdec[ioff + j]);
      bfr[nt] = kb;
    }
#pragma unroll
    for (int mt = 0; mt < 4; ++mt)
#pragma unroll
      for (int nt = 0; nt < 4; ++nt)
        acc[mt][nt] = MFMA16(af[mt], bfr[nt], acc[mt][nt]);
  }
#pragma unroll
  for (int mt = 0; mt < 4; ++mt)
#pragma unroll
    for (int nt = 0; nt < 4; ++nt)
#pragma unroll
      for (int r = 0; r < 4; ++r) {
        const int e = we + mt * 16 + quad * 4 + r;
        const int d = wd + nt * 16 + l16;
        MT[(((long)h * 16 + b) * 128 + e) * 128 + d] = acc[mt][nt][r];
      }
}

// ---------------------------------------------------------------------------
// ST[h][b][e][d] = KV_b[d][e] (bf16); KV_0 = kv_cache, KV_{b+1}=bd*KV_b + M_b
// ---------------------------------------------------------------------------
__global__ __launch_bounds__(256) void kv_scan(const float* __restrict__ MT,
                                               const float* __restrict__ kvc,
                                               const float* __restrict__ slope,
                                               bf16* __restrict__ ST) {
  const long idx = (long)blockIdx.x * 256 + threadIdx.x;
  const int d = idx & 127;
  const int e = (int)((idx >> 7) & 127);
  const int h = (int)(idx >> 14);
  const float s = slope[h];
  const float bd = __expf(-s * 256.f);
  float kv = kvc[((long)h * 128 + d) * 128 + e];
#pragma unroll
  for (int b = 0; b < 16; ++b) {
    const long o = (((long)h * 16 + b) * 128 + e) * 128 + d;
    ST[o] = (bf16)kv;
    kv = bd * kv + MT[o];
  }
}

// ---------------------------------------------------------------------------
// Per-(head,block) attention output -> hidden fp32 [t][h*128+e]
// ---------------------------------------------------------------------------
__global__ __launch_bounds__(512) void attn_out(const bf16* __restrict__ qkvb,
                                                const bf16* __restrict__ vT,
                                                const bf16* __restrict__ ST,
                                                const float* __restrict__ slope,
                                                float* __restrict__ hidden) {
  __shared__ float ddt[257];
  __shared__ bf16 sbuf[8][32][72];
  const int tid = threadIdx.x;
  const int b = blockIdx.x, h = blockIdx.y;
  const float s = slope[h];
  if (tid < 257) ddt[tid] = __expf(-s * (float)tid);
  __syncthreads();
  const int wave = tid >> 6, lane = tid & 63;
  const int quad = lane >> 4, l16 = lane & 15;
  const int iw = wave * 32;
  floatx4 oacc[2][8] = {};
  for (int jb = 0; jb < 4; ++jb) {
    floatx4 sacc[2][4] = {};
#pragma unroll
    for (int kc = 0; kc < 4; ++kc) {
      bf16x8 qf[2], kf[4];
#pragma unroll
      for (int mt = 0; mt < 2; ++mt)
        qf[mt] = *(const bf16x8*)&qkvb[(long)(b * 256 + iw + mt * 16 + l16) * 12288 +
                                       h * 384 + kc * 32 + quad * 8];
#pragma unroll
      for (int nt = 0; nt < 4; ++nt)
        kf[nt] = *(const bf16x8*)&qkvb[(long)(b * 256 + jb * 64 + nt * 16 + l16) * 12288 +
                                       h * 384 + 128 + kc * 32 + quad * 8];
#pragma unroll
      for (int mt = 0; mt < 2; ++mt)
#pragma unroll
        for (int nt = 0; nt < 4; ++nt)
          sacc[mt][nt] = MFMA16(qf[mt], kf[nt], sacc[mt][nt]);
    }
#pragma unroll
    for (int mt = 0; mt < 2; ++mt)
#pragma unroll
      for (int nt = 0; nt < 4; ++nt)
#pragma unroll
        for (int r = 0; r < 4; ++r) {
          const int i = iw + mt * 16 + quad * 4 + r;
          const int j = jb * 64 + nt * 16 + l16;
          const int diff = i - j;
          const float v = (diff >= 0) ? sacc[mt][nt][r] * ddt[diff] : 0.f;
          sbuf[wave][mt * 16 + quad * 4 + r][nt * 16 + l16] = (bf16)v;
        }
    __syncthreads();
#pragma unroll
    for (int kc2 = 0; kc2 < 2; ++kc2) {
      bf16x8 sf[2];
#pragma unroll
      for (int mt = 0; mt < 2; ++mt)
        sf[mt] = *(const bf16x8*)&sbuf[wave][mt * 16 + l16][kc2 * 32 + quad * 8];
#pragma unroll
      for (int et = 0; et < 8; ++et) {
        bf16x8 vf = *(const bf16x8*)&vT[((long)h * 128 + et * 16 + l16) * 4096 +
                                        b * 256 + jb * 64 + kc2 * 32 + quad * 8];
#pragma unroll
        for (int mt = 0; mt < 2; ++mt)
          oacc[mt][et] = MFMA16(sf[mt], vf, oacc[mt][et]);
      }
    }
    __syncthreads();
  }
#pragma unroll
  for (int kc = 0; kc < 4; ++kc) {
    bf16x8 qf[2];
#pragma unroll
    for (int mt = 0; mt < 2; ++mt) {
      bf16x8 q8 = *(const bf16x8*)&qkvb[(long)(b * 256 + iw + mt * 16 + l16) * 12288 +
                                        h * 384 + kc * 32 + quad * 8];
      const float qd = ddt[iw + mt * 16 + l16 + 1];
      bf16x8 qq;
#pragma unroll
      for (int j = 0; j < 8; ++j) qq[j] = (bf16)((float)q8[j] * qd);
      qf[mt] = qq;
    }
#pragma unroll
    for (int et = 0; et < 8; ++et) {
      bf16x8 kvf = *(const bf16x8*)&ST[(((long)h * 16 + b) * 128 + et * 16 + l16) * 128 +
                                       kc * 32 + quad * 8];
#pragma unroll
      for (int mt = 0; mt < 2; ++mt)
        oacc[mt][et] = MFMA16(qf[mt], kvf, oacc[mt][et]);
    }
  }
#pragma unroll
  for (int mt = 0; mt < 2; ++mt)
#pragma unroll
    for (int et = 0; et < 8; ++et)
#pragma unroll
      for (int r = 0; r < 4; ++r) {
        const int t = b * 256 + iw + mt * 16 + quad * 4 + r;
        const int e = et * 16 + l16;
        hidden[(long)t * 4096 + h * 128 + e] = oacc[mt][et][r];
      }
}

// ---------------------------------------------------------------------------
// RMSNorm * norm_weight * gate -> bf16
// ---------------------------------------------------------------------------
__global__ __launch_bounds__(256) void rms_gate(const float* __restrict__ hidden,
                                                const bf16* __restrict__ gateb,
                                                const float* __restrict__ nw,
                                                bf16* __restrict__ afinal) {
  const int t = blockIdx.x, tid = threadIdx.x;
  const float* rowp = hidden + (long)t * 4096;
  float ss = 0.f;
  float4 hv[4];
#pragma unroll
  for (int i = 0; i < 4; ++i) {
    hv[i] = ((const float4*)rowp)[tid + i * 256];
    ss += hv[i].x * hv[i].x + hv[i].y * hv[i].y + hv[i].z * hv[i].z + hv[i].w * hv[i].w;
  }
#pragma unroll
  for (int off = 32; off > 0; off >>= 1) ss += __shfl_down(ss, off);
  __shared__ float red[4];
  if ((tid & 63) == 0) red[tid >> 6] = ss;
  __syncthreads();
  const float tot = red[0] + red[1] + red[2] + red[3];
  const float rs = rsqrtf(tot * (1.f / 4096.f) + 1e-5f);
#pragma unroll
  for (int i = 0; i < 4; ++i) {
    const int c = (tid + i * 256) * 4;
    bf16x4 g = *(const bf16x4*)&gateb[(long)t * 4096 + c];
    float4 w = *(const float4*)&nw[c];
    bf16x4 o;
    o[0] = (bf16)(hv[i].x * rs * w.x * (float)g[0]);
    o[1] = (bf16)(hv[i].y * rs * w.y * (float)g[1]);
    o[2] = (bf16)(hv[i].z * rs * w.z * (float)g[2]);
    o[3] = (bf16)(hv[i].w * rs * w.w * (float)g[3]);
    *(bf16x4*)&afinal[(long)t * 4096 + c] = o;
  }
}

// ---------------------------------------------------------------------------
extern "C" void kernel_launch(void* const* d_in, const int* in_sizes, int n_in,
                              void* d_out, int out_size, void* d_ws, size_t ws_size,
                              hipStream_t stream) {
  (void)in_sizes; (void)n_in; (void)out_size;
  const float* x      = (const float*)d_in[0];
  const float* w_qkv  = (const float*)d_in[1];
  const float* w_gate = (const float*)d_in[2];
  const float* w_out  = (const float*)d_in[3];
  const float* nw     = (const float*)d_in[4];
  const float* kvc    = (const float*)d_in[5];
  const float* slope  = (const float*)d_in[6];
  float* out = (float*)d_out;

  const size_t MB = 1024 * 1024;
  char* base = (char*)d_ws;
  // 384 MB total with aliasing (stream order guarantees safety):
  bf16* qkvb   = (bf16*)(base + 0 * MB);     // 96 MB,  live steps 2..7
  bf16* kT     = (bf16*)(base + 96 * MB);    // 32 MB
  bf16* vT     = (bf16*)(base + 128 * MB);   // 32 MB
  bf16* wob    = (bf16*)(base + 160 * MB);   // 32 MB, live 1..9
  bf16* gateb  = (bf16*)(base + 192 * MB);   // 32 MB, live 3..8
  bf16* xb     = (bf16*)(base + 224 * MB);   // 32 MB, live 1..3
  bf16* afinal = (bf16*)(base + 224 * MB);   // aliases xb (live 8..9)
  bf16* wb     = (bf16*)(base + 256 * MB);   // 128 MB, live 1..3
  float* MT    = (float*)(base + 256 * MB);  // aliases wb (live 5..6)
  bf16* ST     = (bf16*)(base + 288 * MB);   // aliases wb (live 6..7)
  float* hidden= (float*)(base + 304 * MB);  // aliases wb (live 7..8), 64 MB
  if (ws_size < 384 * MB) return;  // clean fail -> visible as absmax blowup

  const long nx = 4096L * 4096, nqkv = 12288L * 4096;
  // 1) fp32 -> bf16 converts
  cvt_bf16<<<dim3((int)(nx / 2048)), 256, 0, stream>>>(x, xb, nx);
  cvt_bf16<<<dim3((int)(nqkv / 2048)), 256, 0, stream>>>(w_qkv, wb, nqkv);
  cvt_bf16<<<dim3((int)(nx / 2048)), 256, 0, stream>>>(w_gate, wb + nqkv, nx);
  cvt_bf16<<<dim3((int)(nx / 2048)), 256, 0, stream>>>(w_out, wob, nx);
  // 2) qkv = silu(x @ w_qkv^T), bf16   (M=4096 -> 16 row-tiles, N=12288 -> 48)
  gemm256<0><<<dim3(16 * 48), 512, 0, stream>>>(xb, wb, qkvb, 12288, 4096);
  // 3) gate = sigmoid(x @ w_gate^T), bf16
  gemm256<1><<<dim3(16 * 16), 512, 0, stream>>>(xb, wb + nqkv, gateb, 4096, 4096);
  // 4) k^T, v^T per head
  transpose_kv<<<dim3(64, 4, 32), 256, 0, stream>>>(qkvb, kT, vT);
  // 5) per-block decayed KV contributions
  kv_blocks<<<dim3(16, 32), 256, 0, stream>>>(kT, vT, slope, MT);
  // 6) sequential-in-b scan -> per-block KV states
  kv_scan<<<dim3(2048), 256, 0, stream>>>(MT, kvc, slope, ST);
  // 7) attention outputs -> hidden
  attn_out<<<dim3(16, 32), 512, 0, stream>>>(qkvb, vT, ST, slope, hidden);
  // 8) RMSNorm * nw * gate -> bf16
  rms_gate<<<dim3(4096), 256, 0, stream>>>(hidden, gateb, nw, afinal);
  // 9) out = afinal @ w_out^T, fp32
  gemm256<2><<<dim3(16 * 16), 512, 0, stream>>>(afinal, wob, out, 4096, 4096);
}